// Round 1
// baseline (1470.831 us; speedup 1.0000x reference)
//
#include <hip/hip_runtime.h>
#include <math.h>

#define E_    8
#define D_    1024
#define F_    4096
#define T_    8192
#define CAP_  2560
#define SP_   (T_ * 2)

typedef __attribute__((ext_vector_type(4))) float f32x4;
typedef __attribute__((ext_vector_type(8))) short bf16x8;

__device__ __forceinline__ float b2f(unsigned short u) {
    union { unsigned int i; float f; } v; v.i = ((unsigned int)u) << 16; return v.f;
}
__device__ __forceinline__ unsigned short f2b(float f) {
    unsigned int u = __float_as_uint(f);
    unsigned int r = (u + 0x7fff + ((u >> 16) & 1)) >> 16;
    return (unsigned short)r;
}
__device__ __forceinline__ void async16(void* lds, const void* g) {
    __builtin_amdgcn_global_load_lds(
        (const __attribute__((address_space(1))) unsigned int*)g,
        (__attribute__((address_space(3))) unsigned int*)lds, 16, 0, 0);
}

// ---------------- router: fp64 logits, top-2, softmax ----------------
__global__ void router_kernel(const float* __restrict__ x, const float* __restrict__ Wr,
                              int* __restrict__ top_i, float* __restrict__ top_w) {
    int wid = threadIdx.x >> 6, lane = threadIdx.x & 63;
    int t = blockIdx.x * 4 + wid;
    double s[E_];
    #pragma unroll
    for (int e = 0; e < E_; e++) s[e] = 0.0;
    const float* xr = x + (size_t)t * D_;
    for (int j = 0; j < D_ / 64; j++) {
        int d = lane + 64 * j;
        double xv = (double)xr[d];
        const float* wr = Wr + d * E_;
        #pragma unroll
        for (int e = 0; e < E_; e++) s[e] += xv * (double)wr[e];
    }
    #pragma unroll
    for (int off = 32; off >= 1; off >>= 1) {
        #pragma unroll
        for (int e = 0; e < E_; e++) s[e] += __shfl_xor(s[e], off, 64);
    }
    if (lane == 0) {
        double best = -1e300, sec = -1e300; int bi = 0, si = 0;
        #pragma unroll
        for (int e = 0; e < E_; e++) {
            double v = s[e];
            v = v > 1e4 ? 1e4 : (v < -1e4 ? -1e4 : v);
            if (v > best) { sec = best; si = bi; best = v; bi = e; }
            else if (v > sec) { sec = v; si = e; }
        }
        double e1 = exp(sec - best);
        double denom = 1.0 + e1 + 1e-12;
        top_i[t * 2 + 0] = bi;  top_i[t * 2 + 1] = si;
        top_w[t * 2 + 0] = (float)(1.0 / denom);
        top_w[t * 2 + 1] = (float)(e1 / denom);
    }
}

// -------- stable per-expert position scan + capacity prune (1 block) --------
#define SCAN_T 256
#define CHUNK  (SP_ / SCAN_T)   // 64
__global__ void scan_kernel(const int* __restrict__ top_i,
                            int* __restrict__ slot,   // [SP_] e*CAP_+pos, or -1
                            int* __restrict__ list,   // [E_*CAP_] pair index
                            int* __restrict__ count)  // [E_]
{
    __shared__ int lc[SCAN_T][E_];
    int tid = threadIdx.x;
    int cnt[E_];
    #pragma unroll
    for (int e = 0; e < E_; e++) cnt[e] = 0;
    int base = tid * CHUNK;
    for (int i = 0; i < CHUNK; i++) cnt[top_i[base + i]]++;
    #pragma unroll
    for (int e = 0; e < E_; e++) lc[tid][e] = cnt[e];
    __syncthreads();
    if (tid < E_) {
        int run = 0;
        for (int i = 0; i < SCAN_T; i++) { int c = lc[i][tid]; lc[i][tid] = run; run += c; }
        count[tid] = run;
    }
    __syncthreads();
    int off[E_];
    #pragma unroll
    for (int e = 0; e < E_; e++) off[e] = lc[tid][e];
    for (int i = 0; i < CHUNK; i++) {
        int s = base + i;
        int e = top_i[s];
        int p = off[e]++;
        if (p < CAP_) { slot[s] = e * CAP_ + p; list[e * CAP_ + p] = s; }
        else slot[s] = -1;
    }
}

// ---------------- dispatch: pack x rows into xe (bf16), zero pads ----------------
__global__ void dispatch_kernel(const float* __restrict__ x, const int* __restrict__ list,
                                const int* __restrict__ count, unsigned short* __restrict__ xe) {
    int c = blockIdx.x, e = blockIdx.y, tid = threadIdx.x;
    unsigned short* dst = xe + ((size_t)e * CAP_ + c) * D_;
    ushort4 o;
    if (c < count[e]) {
        int t = list[e * CAP_ + c] >> 1;
        float4 v = ((const float4*)(x + (size_t)t * D_))[tid];
        o.x = f2b(v.x); o.y = f2b(v.y); o.z = f2b(v.z); o.w = f2b(v.w);
    } else { o.x = 0; o.y = 0; o.z = 0; o.w = 0; }
    ((ushort4*)dst)[tid] = o;
}

// ---------------- transpose + fp32->bf16 convert: src[e][r][c] -> dst[e][c][r] ----------------
__global__ void transpose_conv(const float* __restrict__ src, unsigned short* __restrict__ dst,
                               int R, int C, size_t srcE, size_t dstE) {
    __shared__ float tile[32][33];
    int e = blockIdx.z;
    const float* s = src + (size_t)e * srcE;
    unsigned short* d = dst + (size_t)e * dstE;
    int tx = threadIdx.x, ty = threadIdx.y;
    int c0 = blockIdx.x * 32, r0 = blockIdx.y * 32;
    #pragma unroll
    for (int i = 0; i < 4; i++) tile[ty + i * 8][tx] = s[(size_t)(r0 + ty + i * 8) * C + c0 + tx];
    __syncthreads();
    #pragma unroll
    for (int i = 0; i < 4; i++) d[(size_t)(c0 + ty + i * 8) * R + r0 + tx] = f2b(tile[tx][ty + i * 8]);
}

// ---------------- bf16 GEMM: C[M,N] = A[M,K] * BT[N,K]^T ----------------
// 128x128 tile, BK=64, 4 waves (2x2 of 64x64), 16x16x32 MFMA,
// global_load_lds staging with T2 XOR swizzle (pre-swizzled global source).
__global__ __launch_bounds__(256) void gemm_bt(
    const unsigned short* __restrict__ A, const unsigned short* __restrict__ BT,
    unsigned short* __restrict__ C, int M, int N, int K) {
    __shared__ unsigned short As[128 * 64];
    __shared__ unsigned short Bs[128 * 64];
    int tid = threadIdx.x;
    int lane = tid & 63, wid = tid >> 6;
    int m0 = blockIdx.x * 128, n0 = blockIdx.y * 128;
    int wr = (wid >> 1) * 64, wc = (wid & 1) * 64;
    int lrow = lane & 15, lhi = lane >> 4;

    f32x4 acc[4][4];
    #pragma unroll
    for (int m = 0; m < 4; m++)
        #pragma unroll
        for (int n = 0; n < 4; n++) { f32x4 z = {0.f, 0.f, 0.f, 0.f}; acc[m][n] = z; }

    for (int kt = 0; kt < K; kt += 64) {
        #pragma unroll
        for (int p = 0; p < 4; p++) {
            int ci = p * 256 + tid;
            int row = ci >> 3, cb = ci & 7;
            int scb = cb ^ (row & 7);   // inverse-swizzled global source (rule #21)
            async16(&As[ci * 8], A + (size_t)(m0 + row) * K + kt + scb * 8);
            async16(&Bs[ci * 8], BT + (size_t)(n0 + row) * K + kt + scb * 8);
        }
        __syncthreads();
        #pragma unroll
        for (int kk = 0; kk < 2; kk++) {
            bf16x8 af[4], bf[4];
            #pragma unroll
            for (int m = 0; m < 4; m++) {
                int r = wr + m * 16 + lrow;
                int ch = (kk * 4 + lhi) ^ (r & 7);
                af[m] = *(const bf16x8*)&As[r * 64 + ch * 8];
            }
            #pragma unroll
            for (int n = 0; n < 4; n++) {
                int r = wc + n * 16 + lrow;
                int ch = (kk * 4 + lhi) ^ (r & 7);
                bf[n] = *(const bf16x8*)&Bs[r * 64 + ch * 8];
            }
            #pragma unroll
            for (int m = 0; m < 4; m++)
                #pragma unroll
                for (int n = 0; n < 4; n++)
                    acc[m][n] = __builtin_amdgcn_mfma_f32_16x16x32_bf16(af[m], bf[n], acc[m][n], 0, 0, 0);
        }
        __syncthreads();
    }
    int crow = m0 + wr + lhi * 4;
    int ccol = n0 + wc + lrow;
    #pragma unroll
    for (int m = 0; m < 4; m++)
        #pragma unroll
        for (int n = 0; n < 4; n++)
            #pragma unroll
            for (int r = 0; r < 4; r++)
                C[(size_t)(crow + m * 16 + r) * N + ccol + n * 16] = f2b(acc[m][n][r]);
}

// ---------------- SwiGLU elementwise: H = silu(G[:, :F]) * G[:, F:] ----------------
__global__ void silu_mul(const unsigned short* __restrict__ G, unsigned short* __restrict__ H) {
    size_t idx = ((size_t)blockIdx.x * 256 + threadIdx.x) * 8;   // over CAP_*F_
    size_t c = idx / F_, f = idx % F_;
    const bf16x8 v1 = *(const bf16x8*)(G + c * (2 * F_) + f);
    const bf16x8 v3 = *(const bf16x8*)(G + c * (2 * F_) + F_ + f);
    bf16x8 o;
    #pragma unroll
    for (int j = 0; j < 8; j++) {
        float a = b2f((unsigned short)v1[j]);
        float b = b2f((unsigned short)v3[j]);
        float h = a / (1.f + expf(-a)) * b;
        o[j] = (short)f2b(h);
    }
    *(bf16x8*)(H + c * F_ + f) = o;
}

// ---------------- combine: out[t] = sum_k w[t,k] * Ye[slot(t,k)] ----------------
__global__ void combine_kernel(const unsigned short* __restrict__ Ye, const int* __restrict__ slot,
                               const float* __restrict__ w, float* __restrict__ out) {
    int t = blockIdx.x, tid = threadIdx.x;
    float4 r = {0.f, 0.f, 0.f, 0.f};
    #pragma unroll
    for (int k = 0; k < 2; k++) {
        int s = slot[t * 2 + k];
        if (s >= 0) {
            float wk = w[t * 2 + k];
            ushort4 y = ((const ushort4*)(Ye + (size_t)s * D_))[tid];
            r.x += wk * b2f(y.x); r.y += wk * b2f(y.y);
            r.z += wk * b2f(y.z); r.w += wk * b2f(y.w);
        }
    }
    ((float4*)(out + (size_t)t * D_))[tid] = r;
}

extern "C" void kernel_launch(void* const* d_in, const int* in_sizes, int n_in,
                              void* d_out, int out_size, void* d_ws, size_t ws_size,
                              hipStream_t stream) {
    const float* x  = (const float*)d_in[0];
    const float* Wr = (const float*)d_in[1];
    const float* W1 = (const float*)d_in[2];
    const float* W3 = (const float*)d_in[3];
    const float* W2 = (const float*)d_in[4];
    float* out = (float*)d_out;

    char* ws = (char*)d_ws;
    size_t off = 0;
    auto alloc = [&](size_t bytes) { void* p = ws + off; off += (bytes + 255) & ~(size_t)255; return p; };
    unsigned short* WT13 = (unsigned short*)alloc((size_t)E_ * 2 * F_ * D_ * 2); // [E][2F][D] bf16
    unsigned short* WT2  = (unsigned short*)alloc((size_t)E_ * D_ * F_ * 2);     // [E][D][F] bf16
    unsigned short* xe   = (unsigned short*)alloc((size_t)E_ * CAP_ * D_ * 2);
    unsigned short* Ye   = (unsigned short*)alloc((size_t)E_ * CAP_ * D_ * 2);
    unsigned short* G13  = (unsigned short*)alloc((size_t)CAP_ * 2 * F_ * 2);    // per-expert reuse
    unsigned short* H    = (unsigned short*)alloc((size_t)CAP_ * F_ * 2);        // per-expert reuse
    int*   top_i = (int*)alloc(SP_ * 4);
    float* top_w = (float*)alloc(SP_ * 4);
    int*   slot  = (int*)alloc(SP_ * 4);
    int*   list  = (int*)alloc((size_t)E_ * CAP_ * 4);
    int*   count = (int*)alloc(E_ * 4);

    dim3 tb(32, 8);
    // W1^T -> WT13 rows [0,F), W3^T -> rows [F,2F)
    transpose_conv<<<dim3(F_ / 32, D_ / 32, E_), tb, 0, stream>>>(W1, WT13, D_, F_, (size_t)D_ * F_, (size_t)2 * F_ * D_);
    transpose_conv<<<dim3(F_ / 32, D_ / 32, E_), tb, 0, stream>>>(W3, WT13 + (size_t)F_ * D_, D_, F_, (size_t)D_ * F_, (size_t)2 * F_ * D_);
    transpose_conv<<<dim3(D_ / 32, F_ / 32, E_), tb, 0, stream>>>(W2, WT2, F_, D_, (size_t)F_ * D_, (size_t)D_ * F_);

    router_kernel<<<T_ / 4, 256, 0, stream>>>(x, Wr, top_i, top_w);
    scan_kernel<<<1, SCAN_T, 0, stream>>>(top_i, slot, list, count);
    dispatch_kernel<<<dim3(CAP_, E_), 256, 0, stream>>>(x, list, count, xe);

    for (int e = 0; e < E_; e++) {
        gemm_bt<<<dim3(CAP_ / 128, (2 * F_) / 128), 256, 0, stream>>>(
            xe + (size_t)e * CAP_ * D_, WT13 + (size_t)e * 2 * F_ * D_, G13, CAP_, 2 * F_, D_);
        silu_mul<<<(CAP_ * F_) / (256 * 8), 256, 0, stream>>>(G13, H);
        gemm_bt<<<dim3(CAP_ / 128, D_ / 128), 256, 0, stream>>>(
            H, WT2 + (size_t)e * D_ * F_, Ye + (size_t)e * CAP_ * D_, CAP_, D_, F_);
    }
    combine_kernel<<<T_, 256, 0, stream>>>(Ye, slot, top_w, out);
}

// Round 2
// 1163.015 us; speedup vs baseline: 1.2647x; 1.2647x over previous
//
#include <hip/hip_runtime.h>
#include <math.h>

#define E_    8
#define D_    1024
#define F_    4096
#define T_    8192
#define CAP_  2560
#define SP_   (T_ * 2)
#define EG_   4            // experts per batched launch (ws budget)

typedef __attribute__((ext_vector_type(4))) float f32x4;
typedef __attribute__((ext_vector_type(8))) short bf16x8;

__device__ __forceinline__ float b2f(unsigned short u) {
    union { unsigned int i; float f; } v; v.i = ((unsigned int)u) << 16; return v.f;
}
__device__ __forceinline__ unsigned short f2b(float f) {
    unsigned int u = __float_as_uint(f);
    unsigned int r = (u + 0x7fff + ((u >> 16) & 1)) >> 16;
    return (unsigned short)r;
}
__device__ __forceinline__ void async16(void* lds, const void* g) {
    __builtin_amdgcn_global_load_lds(
        (const __attribute__((address_space(1))) unsigned int*)g,
        (__attribute__((address_space(3))) unsigned int*)lds, 16, 0, 0);
}

// ---------------- router: fp64 logits, top-2, softmax ----------------
__global__ void router_kernel(const float* __restrict__ x, const float* __restrict__ Wr,
                              int* __restrict__ top_i, float* __restrict__ top_w) {
    int wid = threadIdx.x >> 6, lane = threadIdx.x & 63;
    int t = blockIdx.x * 4 + wid;
    double s[E_];
    #pragma unroll
    for (int e = 0; e < E_; e++) s[e] = 0.0;
    const float* xr = x + (size_t)t * D_;
    for (int j = 0; j < D_ / 64; j++) {
        int d = lane + 64 * j;
        double xv = (double)xr[d];
        const float* wr = Wr + d * E_;
        #pragma unroll
        for (int e = 0; e < E_; e++) s[e] += xv * (double)wr[e];
    }
    #pragma unroll
    for (int off = 32; off >= 1; off >>= 1) {
        #pragma unroll
        for (int e = 0; e < E_; e++) s[e] += __shfl_xor(s[e], off, 64);
    }
    if (lane == 0) {
        double best = -1e300, sec = -1e300; int bi = 0, si = 0;
        #pragma unroll
        for (int e = 0; e < E_; e++) {
            double v = s[e];
            v = v > 1e4 ? 1e4 : (v < -1e4 ? -1e4 : v);
            if (v > best) { sec = best; si = bi; best = v; bi = e; }
            else if (v > sec) { sec = v; si = e; }
        }
        double e1 = exp(sec - best);
        double denom = 1.0 + e1 + 1e-12;
        top_i[t * 2 + 0] = bi;  top_i[t * 2 + 1] = si;
        top_w[t * 2 + 0] = (float)(1.0 / denom);
        top_w[t * 2 + 1] = (float)(e1 / denom);
    }
}

// -------- stable per-expert position scan + capacity prune (1 block) --------
#define SCAN_T 256
#define CHUNK  (SP_ / SCAN_T)   // 64
__global__ void scan_kernel(const int* __restrict__ top_i,
                            int* __restrict__ slot,   // [SP_] e*CAP_+pos, or -1
                            int* __restrict__ list,   // [E_*CAP_] pair index
                            int* __restrict__ count)  // [E_]
{
    __shared__ int lc[SCAN_T][E_];
    int tid = threadIdx.x;
    int cnt[E_];
    #pragma unroll
    for (int e = 0; e < E_; e++) cnt[e] = 0;
    int base = tid * CHUNK;
    for (int i = 0; i < CHUNK; i++) cnt[top_i[base + i]]++;
    #pragma unroll
    for (int e = 0; e < E_; e++) lc[tid][e] = cnt[e];
    __syncthreads();
    if (tid < E_) {
        int run = 0;
        for (int i = 0; i < SCAN_T; i++) { int c = lc[i][tid]; lc[i][tid] = run; run += c; }
        count[tid] = run;
    }
    __syncthreads();
    int off[E_];
    #pragma unroll
    for (int e = 0; e < E_; e++) off[e] = lc[tid][e];
    for (int i = 0; i < CHUNK; i++) {
        int s = base + i;
        int e = top_i[s];
        int p = off[e]++;
        if (p < CAP_) { slot[s] = e * CAP_ + p; list[e * CAP_ + p] = s; }
        else slot[s] = -1;
    }
}

// ---------------- dispatch: pack x rows into xe (bf16), zero pads ----------------
__global__ void dispatch_kernel(const float* __restrict__ x, const int* __restrict__ list,
                                const int* __restrict__ count, unsigned short* __restrict__ xe) {
    int c = blockIdx.x, e = blockIdx.y, tid = threadIdx.x;
    unsigned short* dst = xe + ((size_t)e * CAP_ + c) * D_;
    ushort4 o;
    if (c < count[e]) {
        int t = list[e * CAP_ + c] >> 1;
        float4 v = ((const float4*)(x + (size_t)t * D_))[tid];
        o.x = f2b(v.x); o.y = f2b(v.y); o.z = f2b(v.z); o.w = f2b(v.w);
    } else { o.x = 0; o.y = 0; o.z = 0; o.w = 0; }
    ((ushort4*)dst)[tid] = o;
}

// ---------------- transpose + fp32->bf16 convert: src[e][r][c] -> dst[e][c][r] ----------------
__global__ void transpose_conv(const float* __restrict__ src, unsigned short* __restrict__ dst,
                               int R, int C, size_t srcE, size_t dstE) {
    __shared__ float tile[32][33];
    int e = blockIdx.z;
    const float* s = src + (size_t)e * srcE;
    unsigned short* d = dst + (size_t)e * dstE;
    int tx = threadIdx.x, ty = threadIdx.y;
    int c0 = blockIdx.x * 32, r0 = blockIdx.y * 32;
    #pragma unroll
    for (int i = 0; i < 4; i++) tile[ty + i * 8][tx] = s[(size_t)(r0 + ty + i * 8) * C + c0 + tx];
    __syncthreads();
    #pragma unroll
    for (int i = 0; i < 4; i++) d[(size_t)(c0 + ty + i * 8) * R + r0 + tx] = f2b(tile[tx][ty + i * 8]);
}

// ---------------- fused gemm1 + SwiGLU, batched over experts ----------------
// Per block: 128x128 tile of H[e] = silu(xe@W1) * (xe@W3).
// A = xe[e] [CAP,D]; B1 = WT13[e] rows [0,F); B3 = WT13[e] rows [F,2F).
__global__ __launch_bounds__(256) void gemm1_fused(
    const unsigned short* __restrict__ xe,    // [EG][CAP][D]
    const unsigned short* __restrict__ WT13,  // [EG][2F][D]
    unsigned short* __restrict__ H) {         // [EG][CAP][F]
    __shared__ unsigned short As[128 * 64];
    __shared__ unsigned short B1s[128 * 64];
    __shared__ unsigned short B3s[128 * 64];
    int tid = threadIdx.x;
    int lane = tid & 63, wid = tid >> 6;
    int e = blockIdx.z;
    const unsigned short* A  = xe   + (size_t)e * CAP_ * D_;
    const unsigned short* B1 = WT13 + (size_t)e * 2 * F_ * D_;
    const unsigned short* B3 = B1 + (size_t)F_ * D_;
    unsigned short* Hout = H + (size_t)e * CAP_ * F_;
    int m0 = blockIdx.x * 128, n0 = blockIdx.y * 128;
    int wr = (wid >> 1) * 64, wc = (wid & 1) * 64;
    int lrow = lane & 15, lhi = lane >> 4;

    f32x4 acc1[4][4], acc3[4][4];
    #pragma unroll
    for (int m = 0; m < 4; m++)
        #pragma unroll
        for (int n = 0; n < 4; n++) {
            f32x4 z = {0.f, 0.f, 0.f, 0.f};
            acc1[m][n] = z; acc3[m][n] = z;
        }

    for (int kt = 0; kt < D_; kt += 64) {
        #pragma unroll
        for (int p = 0; p < 4; p++) {
            int ci = p * 256 + tid;
            int row = ci >> 3, cb = ci & 7;
            int scb = cb ^ (row & 7);   // inverse-swizzled global source (rule #21)
            async16(&As[ci * 8],  A  + (size_t)(m0 + row) * D_ + kt + scb * 8);
            async16(&B1s[ci * 8], B1 + (size_t)(n0 + row) * D_ + kt + scb * 8);
            async16(&B3s[ci * 8], B3 + (size_t)(n0 + row) * D_ + kt + scb * 8);
        }
        __syncthreads();
        #pragma unroll
        for (int kk = 0; kk < 2; kk++) {
            bf16x8 af[4], b1f[4], b3f[4];
            #pragma unroll
            for (int m = 0; m < 4; m++) {
                int r = wr + m * 16 + lrow;
                int ch = (kk * 4 + lhi) ^ (r & 7);
                af[m] = *(const bf16x8*)&As[r * 64 + ch * 8];
            }
            #pragma unroll
            for (int n = 0; n < 4; n++) {
                int r = wc + n * 16 + lrow;
                int ch = (kk * 4 + lhi) ^ (r & 7);
                b1f[n] = *(const bf16x8*)&B1s[r * 64 + ch * 8];
                b3f[n] = *(const bf16x8*)&B3s[r * 64 + ch * 8];
            }
            #pragma unroll
            for (int m = 0; m < 4; m++)
                #pragma unroll
                for (int n = 0; n < 4; n++) {
                    acc1[m][n] = __builtin_amdgcn_mfma_f32_16x16x32_bf16(af[m], b1f[n], acc1[m][n], 0, 0, 0);
                    acc3[m][n] = __builtin_amdgcn_mfma_f32_16x16x32_bf16(af[m], b3f[n], acc3[m][n], 0, 0, 0);
                }
        }
        __syncthreads();
    }
    int crow = m0 + wr + lhi * 4;
    int ccol = n0 + wc + lrow;
    #pragma unroll
    for (int m = 0; m < 4; m++)
        #pragma unroll
        for (int n = 0; n < 4; n++)
            #pragma unroll
            for (int r = 0; r < 4; r++) {
                float g1 = acc1[m][n][r];
                float g3 = acc3[m][n][r];
                float h = g1 / (1.f + expf(-g1)) * g3;
                Hout[(size_t)(crow + m * 16 + r) * F_ + ccol + n * 16] = f2b(h);
            }
}

// ---------------- bf16 GEMM, batched: C[z] = A[z] * BT[z]^T ----------------
__global__ __launch_bounds__(256) void gemm_bt_bat(
    const unsigned short* __restrict__ Ab, const unsigned short* __restrict__ BTb,
    unsigned short* __restrict__ Cb, int M, int N, int K,
    size_t sA, size_t sB, size_t sC) {
    __shared__ unsigned short As[128 * 64];
    __shared__ unsigned short Bs[128 * 64];
    int tid = threadIdx.x;
    int lane = tid & 63, wid = tid >> 6;
    const unsigned short* A  = Ab  + blockIdx.z * sA;
    const unsigned short* BT = BTb + blockIdx.z * sB;
    unsigned short* C = Cb + blockIdx.z * sC;
    int m0 = blockIdx.x * 128, n0 = blockIdx.y * 128;
    int wr = (wid >> 1) * 64, wc = (wid & 1) * 64;
    int lrow = lane & 15, lhi = lane >> 4;

    f32x4 acc[4][4];
    #pragma unroll
    for (int m = 0; m < 4; m++)
        #pragma unroll
        for (int n = 0; n < 4; n++) { f32x4 z = {0.f, 0.f, 0.f, 0.f}; acc[m][n] = z; }

    for (int kt = 0; kt < K; kt += 64) {
        #pragma unroll
        for (int p = 0; p < 4; p++) {
            int ci = p * 256 + tid;
            int row = ci >> 3, cb = ci & 7;
            int scb = cb ^ (row & 7);
            async16(&As[ci * 8], A + (size_t)(m0 + row) * K + kt + scb * 8);
            async16(&Bs[ci * 8], BT + (size_t)(n0 + row) * K + kt + scb * 8);
        }
        __syncthreads();
        #pragma unroll
        for (int kk = 0; kk < 2; kk++) {
            bf16x8 af[4], bf[4];
            #pragma unroll
            for (int m = 0; m < 4; m++) {
                int r = wr + m * 16 + lrow;
                int ch = (kk * 4 + lhi) ^ (r & 7);
                af[m] = *(const bf16x8*)&As[r * 64 + ch * 8];
            }
            #pragma unroll
            for (int n = 0; n < 4; n++) {
                int r = wc + n * 16 + lrow;
                int ch = (kk * 4 + lhi) ^ (r & 7);
                bf[n] = *(const bf16x8*)&Bs[r * 64 + ch * 8];
            }
            #pragma unroll
            for (int m = 0; m < 4; m++)
                #pragma unroll
                for (int n = 0; n < 4; n++)
                    acc[m][n] = __builtin_amdgcn_mfma_f32_16x16x32_bf16(af[m], bf[n], acc[m][n], 0, 0, 0);
        }
        __syncthreads();
    }
    int crow = m0 + wr + lhi * 4;
    int ccol = n0 + wc + lrow;
    #pragma unroll
    for (int m = 0; m < 4; m++)
        #pragma unroll
        for (int n = 0; n < 4; n++)
            #pragma unroll
            for (int r = 0; r < 4; r++)
                C[(size_t)(crow + m * 16 + r) * N + ccol + n * 16] = f2b(acc[m][n][r]);
}

// ---------------- combine: out[t] = sum_k w[t,k] * Ye[slot(t,k)] ----------------
__global__ void combine_kernel(const unsigned short* __restrict__ Ye, const int* __restrict__ slot,
                               const float* __restrict__ w, float* __restrict__ out) {
    int t = blockIdx.x, tid = threadIdx.x;
    float4 r = {0.f, 0.f, 0.f, 0.f};
    #pragma unroll
    for (int k = 0; k < 2; k++) {
        int s = slot[t * 2 + k];
        if (s >= 0) {
            float wk = w[t * 2 + k];
            ushort4 y = ((const ushort4*)(Ye + (size_t)s * D_))[tid];
            r.x += wk * b2f(y.x); r.y += wk * b2f(y.y);
            r.z += wk * b2f(y.z); r.w += wk * b2f(y.w);
        }
    }
    ((float4*)(out + (size_t)t * D_))[tid] = r;
}

extern "C" void kernel_launch(void* const* d_in, const int* in_sizes, int n_in,
                              void* d_out, int out_size, void* d_ws, size_t ws_size,
                              hipStream_t stream) {
    const float* x  = (const float*)d_in[0];
    const float* Wr = (const float*)d_in[1];
    const float* W1 = (const float*)d_in[2];
    const float* W3 = (const float*)d_in[3];
    const float* W2 = (const float*)d_in[4];
    float* out = (float*)d_out;

    char* ws = (char*)d_ws;
    size_t off = 0;
    auto alloc = [&](size_t bytes) { void* p = ws + off; off += (bytes + 255) & ~(size_t)255; return p; };
    unsigned short* WT13 = (unsigned short*)alloc((size_t)E_ * 2 * F_ * D_ * 2); // [E][2F][D] bf16
    unsigned short* WT2  = (unsigned short*)alloc((size_t)E_ * D_ * F_ * 2);     // [E][D][F] bf16
    unsigned short* xe   = (unsigned short*)alloc((size_t)E_ * CAP_ * D_ * 2);
    unsigned short* Ye   = (unsigned short*)alloc((size_t)E_ * CAP_ * D_ * 2);
    unsigned short* Hg   = (unsigned short*)alloc((size_t)EG_ * CAP_ * F_ * 2);  // per-group reuse
    int*   top_i = (int*)alloc(SP_ * 4);
    float* top_w = (float*)alloc(SP_ * 4);
    int*   slot  = (int*)alloc(SP_ * 4);
    int*   list  = (int*)alloc((size_t)E_ * CAP_ * 4);
    int*   count = (int*)alloc(E_ * 4);

    dim3 tb(32, 8);
    transpose_conv<<<dim3(F_ / 32, D_ / 32, E_), tb, 0, stream>>>(W1, WT13, D_, F_, (size_t)D_ * F_, (size_t)2 * F_ * D_);
    transpose_conv<<<dim3(F_ / 32, D_ / 32, E_), tb, 0, stream>>>(W3, WT13 + (size_t)F_ * D_, D_, F_, (size_t)D_ * F_, (size_t)2 * F_ * D_);
    transpose_conv<<<dim3(D_ / 32, F_ / 32, E_), tb, 0, stream>>>(W2, WT2, F_, D_, (size_t)F_ * D_, (size_t)D_ * F_);

    router_kernel<<<T_ / 4, 256, 0, stream>>>(x, Wr, top_i, top_w);
    scan_kernel<<<1, SCAN_T, 0, stream>>>(top_i, slot, list, count);
    dispatch_kernel<<<dim3(CAP_, E_), 256, 0, stream>>>(x, list, count, xe);

    for (int g = 0; g < E_ / EG_; g++) {
        size_t eo = (size_t)g * EG_;
        gemm1_fused<<<dim3(CAP_ / 128, F_ / 128, EG_), 256, 0, stream>>>(
            xe + eo * CAP_ * D_, WT13 + eo * 2 * F_ * D_, Hg);
        gemm_bt_bat<<<dim3(CAP_ / 128, D_ / 128, EG_), 256, 0, stream>>>(
            Hg, WT2 + eo * D_ * F_, Ye + eo * CAP_ * D_, CAP_, D_, F_,
            (size_t)CAP_ * F_, (size_t)D_ * F_, (size_t)CAP_ * D_);
    }
    combine_kernel<<<T_, 256, 0, stream>>>(Ye, slot, top_w, out);
}

// Round 3
// 933.546 us; speedup vs baseline: 1.5755x; 1.2458x over previous
//
#include <hip/hip_runtime.h>
#include <math.h>

#define E_    8
#define D_    1024
#define F_    4096
#define T_    8192
#define CAP_  2560
#define SP_   (T_ * 2)
#define EG_   4            // experts per batched launch (ws budget)

typedef __attribute__((ext_vector_type(4))) float f32x4;
typedef __attribute__((ext_vector_type(8))) short bf16x8;

__device__ __forceinline__ float b2f(unsigned short u) {
    union { unsigned int i; float f; } v; v.i = ((unsigned int)u) << 16; return v.f;
}
__device__ __forceinline__ unsigned short f2b(float f) {
    unsigned int u = __float_as_uint(f);
    unsigned int r = (u + 0x7fff + ((u >> 16) & 1)) >> 16;
    return (unsigned short)r;
}
__device__ __forceinline__ void async16(void* lds, const void* g) {
    __builtin_amdgcn_global_load_lds(
        (const __attribute__((address_space(1))) unsigned int*)g,
        (__attribute__((address_space(3))) unsigned int*)lds, 16, 0, 0);
}

// Stage one 128x64-bf16 half-tile: linear LDS dest (gload_lds), inverse-swizzled
// global source (rule #21).  512 threads x 2 x 16B = 16KB.
__device__ __forceinline__ void stage128x64(unsigned short* ldsb, const unsigned short* g,
                                            int ldk, int tid) {
    #pragma unroll
    for (int j = 0; j < 2; j++) {
        int ei = j * 512 + tid;
        int r = ei >> 3, c = ei & 7;
        async16(ldsb + ei * 8, g + (size_t)r * ldk + ((c ^ (r & 7)) * 8));
    }
}

// ---------------- router: fp64 logits, top-2, softmax ----------------
__global__ void router_kernel(const float* __restrict__ x, const float* __restrict__ Wr,
                              int* __restrict__ top_i, float* __restrict__ top_w) {
    int wid = threadIdx.x >> 6, lane = threadIdx.x & 63;
    int t = blockIdx.x * 4 + wid;
    double s[E_];
    #pragma unroll
    for (int e = 0; e < E_; e++) s[e] = 0.0;
    const float* xr = x + (size_t)t * D_;
    for (int j = 0; j < D_ / 64; j++) {
        int d = lane + 64 * j;
        double xv = (double)xr[d];
        const float* wr = Wr + d * E_;
        #pragma unroll
        for (int e = 0; e < E_; e++) s[e] += xv * (double)wr[e];
    }
    #pragma unroll
    for (int off = 32; off >= 1; off >>= 1) {
        #pragma unroll
        for (int e = 0; e < E_; e++) s[e] += __shfl_xor(s[e], off, 64);
    }
    if (lane == 0) {
        double best = -1e300, sec = -1e300; int bi = 0, si = 0;
        #pragma unroll
        for (int e = 0; e < E_; e++) {
            double v = s[e];
            v = v > 1e4 ? 1e4 : (v < -1e4 ? -1e4 : v);
            if (v > best) { sec = best; si = bi; best = v; bi = e; }
            else if (v > sec) { sec = v; si = e; }
        }
        double e1 = exp(sec - best);
        double denom = 1.0 + e1 + 1e-12;
        top_i[t * 2 + 0] = bi;  top_i[t * 2 + 1] = si;
        top_w[t * 2 + 0] = (float)(1.0 / denom);
        top_w[t * 2 + 1] = (float)(e1 / denom);
    }
}

// -------- stable per-expert position scan + capacity prune (1 block) --------
#define SCAN_T 256
#define CHUNK  (SP_ / SCAN_T)   // 64
__global__ void scan_kernel(const int* __restrict__ top_i,
                            int* __restrict__ slot,   // [SP_] e*CAP_+pos, or -1
                            int* __restrict__ list,   // [E_*CAP_] pair index
                            int* __restrict__ count)  // [E_]
{
    __shared__ int lc[SCAN_T][E_];
    int tid = threadIdx.x;
    int cnt[E_];
    #pragma unroll
    for (int e = 0; e < E_; e++) cnt[e] = 0;
    int base = tid * CHUNK;
    for (int i = 0; i < CHUNK; i++) cnt[top_i[base + i]]++;
    #pragma unroll
    for (int e = 0; e < E_; e++) lc[tid][e] = cnt[e];
    __syncthreads();
    if (tid < E_) {
        int run = 0;
        for (int i = 0; i < SCAN_T; i++) { int c = lc[i][tid]; lc[i][tid] = run; run += c; }
        count[tid] = run;
    }
    __syncthreads();
    int off[E_];
    #pragma unroll
    for (int e = 0; e < E_; e++) off[e] = lc[tid][e];
    for (int i = 0; i < CHUNK; i++) {
        int s = base + i;
        int e = top_i[s];
        int p = off[e]++;
        if (p < CAP_) { slot[s] = e * CAP_ + p; list[e * CAP_ + p] = s; }
        else slot[s] = -1;
    }
}

// ---------------- dispatch: pack x rows into xe (bf16), zero pads ----------------
__global__ void dispatch_kernel(const float* __restrict__ x, const int* __restrict__ list,
                                const int* __restrict__ count, unsigned short* __restrict__ xe) {
    int c = blockIdx.x, e = blockIdx.y, tid = threadIdx.x;
    unsigned short* dst = xe + ((size_t)e * CAP_ + c) * D_;
    ushort4 o;
    if (c < count[e]) {
        int t = list[e * CAP_ + c] >> 1;
        float4 v = ((const float4*)(x + (size_t)t * D_))[tid];
        o.x = f2b(v.x); o.y = f2b(v.y); o.z = f2b(v.z); o.w = f2b(v.w);
    } else { o.x = 0; o.y = 0; o.z = 0; o.w = 0; }
    ((ushort4*)dst)[tid] = o;
}

// ---------------- transpose + fp32->bf16 convert: src[e][r][c] -> dst[e][c][r] ----------------
__global__ void transpose_conv(const float* __restrict__ src, unsigned short* __restrict__ dst,
                               int R, int C, size_t srcE, size_t dstE) {
    __shared__ float tile[32][33];
    int e = blockIdx.z;
    const float* s = src + (size_t)e * srcE;
    unsigned short* d = dst + (size_t)e * dstE;
    int tx = threadIdx.x, ty = threadIdx.y;
    int c0 = blockIdx.x * 32, r0 = blockIdx.y * 32;
    #pragma unroll
    for (int i = 0; i < 4; i++) tile[ty + i * 8][tx] = s[(size_t)(r0 + ty + i * 8) * C + c0 + tx];
    __syncthreads();
    #pragma unroll
    for (int i = 0; i < 4; i++) d[(size_t)(c0 + ty + i * 8) * R + r0 + tx] = f2b(tile[tx][ty + i * 8]);
}

// ============================================================================
// gemm1_8p: H[e] = silu(xe@W1) * (xe@W3), 8-phase counted-vmcnt schedule.
// BM=256, BN=128, BK=64, 8 waves (2M x 4N), wave output 128x32 per acc set.
// LDS 128KB: A 2buf x 2half x 16KB, B1 2buf x 16KB, B3 2buf x 16KB.
// Steady state per iteration (K-tiles t=2it -> buf0, t+1 -> buf1):
//   P1 reads buf0 A(m0,1)+B; stage buf1.A0<-t+1
//   P2 reads buf0 A(m2,3);   stage buf1.A1<-t+1
//   P3 reads buf0 A(m4,5);   stage buf0.B1<-t+2
//   P4 reads buf0 A(m6,7);   stage buf0.B3<-t+2; vmcnt(4)  [t+1 landed]
//   P5..P8 mirror on buf1;   stages buf0.A<-t+2, buf1.B<-t+3; vmcnt(4) at P8
// Slot-freedom: every stage is issued >=1 barrier after its slot's last read.
// ============================================================================
#define G1_PHASE(ABUF, MP, LOADB, BBUF, STAGE, VMC)                            \
  {                                                                            \
    const unsigned short* Ah = As + (ABUF) * 16384 + wr * 8192;                \
    bf16x8 af[2][2];                                                           \
    _Pragma("unroll")                                                          \
    for (int mi = 0; mi < 2; mi++) {                                           \
      int r = ((MP) * 2 + mi) * 16 + lrow;                                     \
      _Pragma("unroll")                                                        \
      for (int kk = 0; kk < 2; kk++)                                           \
        af[mi][kk] = *(const bf16x8*)(Ah + (r * 8 + ((kk * 4 + lhi) ^ (r & 7))) * 8); \
    }                                                                          \
    if (LOADB) {                                                               \
      _Pragma("unroll")                                                        \
      for (int n = 0; n < 2; n++) {                                            \
        int rb = wc * 32 + n * 16 + lrow;                                      \
        _Pragma("unroll")                                                      \
        for (int kk = 0; kk < 2; kk++) {                                       \
          int ofs = (rb * 8 + ((kk * 4 + lhi) ^ (rb & 7))) * 8;                \
          b1f[n][kk] = *(const bf16x8*)(B1s + (BBUF) * 8192 + ofs);            \
          b3f[n][kk] = *(const bf16x8*)(B3s + (BBUF) * 8192 + ofs);            \
        }                                                                      \
      }                                                                        \
    }                                                                          \
    STAGE;                                                                     \
    __builtin_amdgcn_s_barrier();                                              \
    asm volatile("s_waitcnt lgkmcnt(0)" ::: "memory");                         \
    __builtin_amdgcn_sched_barrier(0);                                         \
    __builtin_amdgcn_s_setprio(1);                                             \
    _Pragma("unroll")                                                          \
    for (int mi = 0; mi < 2; mi++)                                             \
      _Pragma("unroll")                                                        \
      for (int n = 0; n < 2; n++)                                              \
        _Pragma("unroll")                                                      \
        for (int kk = 0; kk < 2; kk++) {                                       \
          acc1[(MP) * 2 + mi][n] = __builtin_amdgcn_mfma_f32_16x16x32_bf16(    \
              af[mi][kk], b1f[n][kk], acc1[(MP) * 2 + mi][n], 0, 0, 0);        \
          acc3[(MP) * 2 + mi][n] = __builtin_amdgcn_mfma_f32_16x16x32_bf16(    \
              af[mi][kk], b3f[n][kk], acc3[(MP) * 2 + mi][n], 0, 0, 0);        \
        }                                                                      \
    __builtin_amdgcn_s_setprio(0);                                             \
    if (VMC) asm volatile("s_waitcnt vmcnt(4)" ::: "memory");                  \
    __builtin_amdgcn_s_barrier();                                              \
  }

__global__ __launch_bounds__(512, 2) void gemm1_8p(
    const unsigned short* __restrict__ xe,    // [EG][CAP][D]
    const unsigned short* __restrict__ WT13,  // [EG][2F][D]
    unsigned short* __restrict__ H) {         // [EG][CAP][F]
    __shared__ unsigned short As[2 * 2 * 8192];   // 64KB
    __shared__ unsigned short B1s[2 * 8192];      // 32KB
    __shared__ unsigned short B3s[2 * 8192];      // 32KB
    const int tid = threadIdx.x;
    const int lane = tid & 63, wid = tid >> 6;
    const int wr = wid >> 2, wc = wid & 3;
    const int lrow = lane & 15, lhi = lane >> 4;
    const int e = blockIdx.z;
    const int m0 = blockIdx.x * 256, n0 = blockIdx.y * 128;
    const unsigned short* A  = xe + (size_t)e * CAP_ * D_ + (size_t)m0 * D_;
    const unsigned short* B1 = WT13 + (size_t)e * 2 * F_ * D_ + (size_t)n0 * D_;
    const unsigned short* B3 = B1 + (size_t)F_ * D_;
    unsigned short* Hout = H + (size_t)e * CAP_ * F_;

    f32x4 acc1[8][2], acc3[8][2];
    #pragma unroll
    for (int m = 0; m < 8; m++)
        #pragma unroll
        for (int n = 0; n < 2; n++) {
            f32x4 z = {0.f, 0.f, 0.f, 0.f};
            acc1[m][n] = z; acc3[m][n] = z;
        }
    bf16x8 b1f[2][2], b3f[2][2];

    // prologue: buf0 <- K-tile 0 (A0,A1,B1,B3); buf1.B <- K-tile 1
    stage128x64(As,            A, D_, tid);
    stage128x64(As + 8192,     A + (size_t)128 * D_, D_, tid);
    stage128x64(B1s,           B1, D_, tid);
    stage128x64(B3s,           B3, D_, tid);
    stage128x64(B1s + 8192,    B1 + 64, D_, tid);
    stage128x64(B3s + 8192,    B3 + 64, D_, tid);
    asm volatile("s_waitcnt vmcnt(4)" ::: "memory");   // buf0 landed; buf1.B in flight
    __builtin_amdgcn_s_barrier();

    for (int it = 0; it < 8; ++it) {                   // NT=16, 2 K-tiles/iter
        const int t = 2 * it;
        const int k1 = (t + 1) * 64;
        const int k2 = (t + 2 < 16 ? t + 2 : 15) * 64;
        const int k3 = (t + 3 < 16 ? t + 3 : 15) * 64;
        G1_PHASE(0, 0, 1, 0, stage128x64(As + 16384,        A + k1, D_, tid), 0)
        G1_PHASE(0, 1, 0, 0, stage128x64(As + 16384 + 8192, A + (size_t)128 * D_ + k1, D_, tid), 0)
        G1_PHASE(0, 2, 0, 0, stage128x64(B1s,               B1 + k2, D_, tid), 0)
        G1_PHASE(0, 3, 0, 0, stage128x64(B3s,               B3 + k2, D_, tid), 1)
        G1_PHASE(1, 0, 1, 1, stage128x64(As,                A + k2, D_, tid), 0)
        G1_PHASE(1, 1, 0, 1, stage128x64(As + 8192,         A + (size_t)128 * D_ + k2, D_, tid), 0)
        G1_PHASE(1, 2, 0, 1, stage128x64(B1s + 8192,        B1 + k3, D_, tid), 0)
        G1_PHASE(1, 3, 0, 1, stage128x64(B3s + 8192,        B3 + k3, D_, tid), 1)
    }

    const int crow = m0 + wr * 128 + lhi * 4;
    const int ccol = n0 + wc * 32 + lrow;
    #pragma unroll
    for (int m = 0; m < 8; m++)
        #pragma unroll
        for (int n = 0; n < 2; n++)
            #pragma unroll
            for (int r = 0; r < 4; r++) {
                float g1 = acc1[m][n][r], g3 = acc3[m][n][r];
                float h = g1 / (1.f + expf(-g1)) * g3;
                Hout[(size_t)(crow + m * 16 + r) * F_ + ccol + n * 16] = f2b(h);
            }
}

// ============================================================================
// gemm2_4p: Ye[e] = H[e] @ WT2[e]^T, 4-phase counted-vmcnt schedule.
// BM=256, BN=128, BK=64, 8 waves (2M x 4N), wave output 128x32.
// LDS 96KB: A 2buf x 2half x 16KB, B 2buf x 16KB.
//   P1 reads buf0 A(m0-3)+B; stage buf1.A0,A1<-t+1
//   P2 reads buf0 A(m4-7);   stage buf0.B<-t+2; vmcnt(2) [t+1 landed]
//   P3 reads buf1 A(m0-3)+B; stage buf0.A0,A1<-t+2
//   P4 reads buf1 A(m4-7);   stage buf1.B<-t+3; vmcnt(2) [t+2 landed]
// ============================================================================
#define G2_PHASE(ABUF, MH, LOADB, BBUF, STAGE, VMC)                            \
  {                                                                            \
    const unsigned short* Ah = As + (ABUF) * 16384 + wr * 8192;                \
    bf16x8 af[4][2];                                                           \
    _Pragma("unroll")                                                          \
    for (int mi = 0; mi < 4; mi++) {                                           \
      int r = ((MH) * 4 + mi) * 16 + lrow;                                     \
      _Pragma("unroll")                                                        \
      for (int kk = 0; kk < 2; kk++)                                           \
        af[mi][kk] = *(const bf16x8*)(Ah + (r * 8 + ((kk * 4 + lhi) ^ (r & 7))) * 8); \
    }                                                                          \
    if (LOADB) {                                                               \
      _Pragma("unroll")                                                        \
      for (int n = 0; n < 2; n++) {                                            \
        int rb = wc * 32 + n * 16 + lrow;                                      \
        _Pragma("unroll")                                                      \
        for (int kk = 0; kk < 2; kk++)                                         \
          bf[n][kk] = *(const bf16x8*)(Bs + (BBUF) * 8192 +                    \
                                       (rb * 8 + ((kk * 4 + lhi) ^ (rb & 7))) * 8); \
      }                                                                        \
    }                                                                          \
    STAGE;                                                                     \
    __builtin_amdgcn_s_barrier();                                              \
    asm volatile("s_waitcnt lgkmcnt(0)" ::: "memory");                         \
    __builtin_amdgcn_sched_barrier(0);                                         \
    __builtin_amdgcn_s_setprio(1);                                             \
    _Pragma("unroll")                                                          \
    for (int mi = 0; mi < 4; mi++)                                             \
      _Pragma("unroll")                                                        \
      for (int n = 0; n < 2; n++)                                              \
        _Pragma("unroll")                                                      \
        for (int kk = 0; kk < 2; kk++)                                         \
          acc[(MH) * 4 + mi][n] = __builtin_amdgcn_mfma_f32_16x16x32_bf16(     \
              af[mi][kk], bf[n][kk], acc[(MH) * 4 + mi][n], 0, 0, 0);          \
    __builtin_amdgcn_s_setprio(0);                                             \
    if (VMC) asm volatile("s_waitcnt vmcnt(2)" ::: "memory");                  \
    __builtin_amdgcn_s_barrier();                                              \
  }

__global__ __launch_bounds__(512, 2) void gemm2_4p(
    const unsigned short* __restrict__ Hb,   // [EG][CAP][F]
    const unsigned short* __restrict__ WT2,  // [EG][D][F]
    unsigned short* __restrict__ Ye) {       // [EG][CAP][D]
    __shared__ unsigned short As[2 * 2 * 8192];   // 64KB
    __shared__ unsigned short Bs[2 * 8192];       // 32KB
    const int tid = threadIdx.x;
    const int lane = tid & 63, wid = tid >> 6;
    const int wr = wid >> 2, wc = wid & 3;
    const int lrow = lane & 15, lhi = lane >> 4;
    const int e = blockIdx.z;
    const int m0 = blockIdx.x * 256, n0 = blockIdx.y * 128;
    const unsigned short* A = Hb + (size_t)e * CAP_ * F_ + (size_t)m0 * F_;
    const unsigned short* B = WT2 + (size_t)e * D_ * F_ + (size_t)n0 * F_;
    unsigned short* C = Ye + (size_t)e * CAP_ * D_;

    f32x4 acc[8][2];
    #pragma unroll
    for (int m = 0; m < 8; m++)
        #pragma unroll
        for (int n = 0; n < 2; n++) { f32x4 z = {0.f, 0.f, 0.f, 0.f}; acc[m][n] = z; }
    bf16x8 bf[2][2];

    // prologue: buf0 <- K-tile 0 (A0,A1,B); buf1.B <- K-tile 1
    stage128x64(As,         A, F_, tid);
    stage128x64(As + 8192,  A + (size_t)128 * F_, F_, tid);
    stage128x64(Bs,         B, F_, tid);
    stage128x64(Bs + 8192,  B + 64, F_, tid);
    asm volatile("s_waitcnt vmcnt(2)" ::: "memory");
    __builtin_amdgcn_s_barrier();

    for (int it = 0; it < 32; ++it) {                 // NT=64, 2 K-tiles/iter
        const int t = 2 * it;
        const int k1 = (t + 1) * 64;
        const int k2 = (t + 2 < 64 ? t + 2 : 63) * 64;
        const int k3 = (t + 3 < 64 ? t + 3 : 63) * 64;
        G2_PHASE(0, 0, 1, 0,
                 stage128x64(As + 16384, A + k1, F_, tid);
                 stage128x64(As + 16384 + 8192, A + (size_t)128 * F_ + k1, F_, tid), 0)
        G2_PHASE(0, 1, 0, 0, stage128x64(Bs, B + k2, F_, tid), 1)
        G2_PHASE(1, 0, 1, 1,
                 stage128x64(As, A + k2, F_, tid);
                 stage128x64(As + 8192, A + (size_t)128 * F_ + k2, F_, tid), 0)
        G2_PHASE(1, 1, 0, 1, stage128x64(Bs + 8192, B + k3, F_, tid), 1)
    }

    const int crow = m0 + wr * 128 + lhi * 4;
    const int ccol = n0 + wc * 32 + lrow;
    #pragma unroll
    for (int m = 0; m < 8; m++)
        #pragma unroll
        for (int n = 0; n < 2; n++)
            #pragma unroll
            for (int r = 0; r < 4; r++)
                C[(size_t)(crow + m * 16 + r) * D_ + ccol + n * 16] = f2b(acc[m][n][r]);
}

// ---------------- combine: out[t] = sum_k w[t,k] * Ye[slot(t,k)] ----------------
__global__ void combine_kernel(const unsigned short* __restrict__ Ye, const int* __restrict__ slot,
                               const float* __restrict__ w, float* __restrict__ out) {
    int t = blockIdx.x, tid = threadIdx.x;
    float4 r = {0.f, 0.f, 0.f, 0.f};
    #pragma unroll
    for (int k = 0; k < 2; k++) {
        int s = slot[t * 2 + k];
        if (s >= 0) {
            float wk = w[t * 2 + k];
            ushort4 y = ((const ushort4*)(Ye + (size_t)s * D_))[tid];
            r.x += wk * b2f(y.x); r.y += wk * b2f(y.y);
            r.z += wk * b2f(y.z); r.w += wk * b2f(y.w);
        }
    }
    ((float4*)(out + (size_t)t * D_))[tid] = r;
}

extern "C" void kernel_launch(void* const* d_in, const int* in_sizes, int n_in,
                              void* d_out, int out_size, void* d_ws, size_t ws_size,
                              hipStream_t stream) {
    const float* x  = (const float*)d_in[0];
    const float* Wr = (const float*)d_in[1];
    const float* W1 = (const float*)d_in[2];
    const float* W3 = (const float*)d_in[3];
    const float* W2 = (const float*)d_in[4];
    float* out = (float*)d_out;

    char* ws = (char*)d_ws;
    size_t off = 0;
    auto alloc = [&](size_t bytes) { void* p = ws + off; off += (bytes + 255) & ~(size_t)255; return p; };
    unsigned short* WT13 = (unsigned short*)alloc((size_t)E_ * 2 * F_ * D_ * 2); // [E][2F][D] bf16
    unsigned short* WT2  = (unsigned short*)alloc((size_t)E_ * D_ * F_ * 2);     // [E][D][F] bf16
    unsigned short* xe   = (unsigned short*)alloc((size_t)E_ * CAP_ * D_ * 2);
    unsigned short* Ye   = (unsigned short*)alloc((size_t)E_ * CAP_ * D_ * 2);
    unsigned short* Hg   = (unsigned short*)alloc((size_t)EG_ * CAP_ * F_ * 2);  // per-group reuse
    int*   top_i = (int*)alloc(SP_ * 4);
    float* top_w = (float*)alloc(SP_ * 4);
    int*   slot  = (int*)alloc(SP_ * 4);
    int*   list  = (int*)alloc((size_t)E_ * CAP_ * 4);
    int*   count = (int*)alloc(E_ * 4);

    dim3 tb(32, 8);
    transpose_conv<<<dim3(F_ / 32, D_ / 32, E_), tb, 0, stream>>>(W1, WT13, D_, F_, (size_t)D_ * F_, (size_t)2 * F_ * D_);
    transpose_conv<<<dim3(F_ / 32, D_ / 32, E_), tb, 0, stream>>>(W3, WT13 + (size_t)F_ * D_, D_, F_, (size_t)D_ * F_, (size_t)2 * F_ * D_);
    transpose_conv<<<dim3(D_ / 32, F_ / 32, E_), tb, 0, stream>>>(W2, WT2, F_, D_, (size_t)F_ * D_, (size_t)D_ * F_);

    router_kernel<<<T_ / 4, 256, 0, stream>>>(x, Wr, top_i, top_w);
    scan_kernel<<<1, SCAN_T, 0, stream>>>(top_i, slot, list, count);
    dispatch_kernel<<<dim3(CAP_, E_), 256, 0, stream>>>(x, list, count, xe);

    for (int g = 0; g < E_ / EG_; g++) {
        size_t eo = (size_t)g * EG_;
        gemm1_8p<<<dim3(CAP_ / 256, F_ / 128, EG_), 512, 0, stream>>>(
            xe + eo * CAP_ * D_, WT13 + eo * 2 * F_ * D_, Hg);
        gemm2_4p<<<dim3(CAP_ / 256, D_ / 128, EG_), 512, 0, stream>>>(
            Hg, WT2 + eo * D_ * F_, Ye + eo * CAP_ * D_);
    }
    combine_kernel<<<T_, 256, 0, stream>>>(Ye, slot, top_w, out);
}

// Round 4
// 766.669 us; speedup vs baseline: 1.9185x; 1.2177x over previous
//
#include <hip/hip_runtime.h>
#include <math.h>

#define E_    8
#define D_    1024
#define F_    4096
#define T_    8192
#define CAP_  2560
#define SP_   (T_ * 2)
#define EG_   4            // experts per batched launch (ws budget)

typedef __attribute__((ext_vector_type(4))) float f32x4;
typedef __attribute__((ext_vector_type(8))) short bf16x8;

__device__ __forceinline__ float b2f(unsigned short u) {
    union { unsigned int i; float f; } v; v.i = ((unsigned int)u) << 16; return v.f;
}
__device__ __forceinline__ unsigned short f2b(float f) {
    unsigned int u = __float_as_uint(f);
    unsigned int r = (u + 0x7fff + ((u >> 16) & 1)) >> 16;
    return (unsigned short)r;
}
__device__ __forceinline__ void async16(void* lds, const void* g) {
    __builtin_amdgcn_global_load_lds(
        (const __attribute__((address_space(1))) unsigned int*)g,
        (__attribute__((address_space(3))) unsigned int*)lds, 16, 0, 0);
}

// Stage one 64x64-bf16 chunk (8KB): linear LDS dest (gload_lds), inverse-swizzled
// global source (rule #21).  512 threads x 1 x 16B.
__device__ __forceinline__ void stage64(unsigned short* ldsb, const unsigned short* g,
                                        int ldk, int tid) {
    int r = tid >> 3, c = tid & 7;
    async16(ldsb + tid * 8, g + (size_t)r * ldk + ((c ^ (r & 7)) * 8));
}
// 128x64 half-tile (16KB) = 2 chunks, 2 loads/thread.
__device__ __forceinline__ void stage128x64(unsigned short* ldsb, const unsigned short* g,
                                            int ldk, int tid) {
    stage64(ldsb, g, ldk, tid);
    stage64(ldsb + 4096, g + (size_t)64 * ldk, ldk, tid);
}

// ---------------- router: fp64 logits, top-2, softmax ----------------
__global__ void router_kernel(const float* __restrict__ x, const float* __restrict__ Wr,
                              int* __restrict__ top_i, float* __restrict__ top_w) {
    int wid = threadIdx.x >> 6, lane = threadIdx.x & 63;
    int t = blockIdx.x * 4 + wid;
    double s[E_];
    #pragma unroll
    for (int e = 0; e < E_; e++) s[e] = 0.0;
    const float* xr = x + (size_t)t * D_;
    for (int j = 0; j < D_ / 64; j++) {
        int d = lane + 64 * j;
        double xv = (double)xr[d];
        const float* wr = Wr + d * E_;
        #pragma unroll
        for (int e = 0; e < E_; e++) s[e] += xv * (double)wr[e];
    }
    #pragma unroll
    for (int off = 32; off >= 1; off >>= 1) {
        #pragma unroll
        for (int e = 0; e < E_; e++) s[e] += __shfl_xor(s[e], off, 64);
    }
    if (lane == 0) {
        double best = -1e300, sec = -1e300; int bi = 0, si = 0;
        #pragma unroll
        for (int e = 0; e < E_; e++) {
            double v = s[e];
            v = v > 1e4 ? 1e4 : (v < -1e4 ? -1e4 : v);
            if (v > best) { sec = best; si = bi; best = v; bi = e; }
            else if (v > sec) { sec = v; si = e; }
        }
        double e1 = exp(sec - best);
        double denom = 1.0 + e1 + 1e-12;
        top_i[t * 2 + 0] = bi;  top_i[t * 2 + 1] = si;
        top_w[t * 2 + 0] = (float)(1.0 / denom);
        top_w[t * 2 + 1] = (float)(e1 / denom);
    }
}

// -------- stable per-expert position scan + capacity prune (1 block) --------
#define SCAN_T 256
#define CHUNK  (SP_ / SCAN_T)   // 64
__global__ void scan_kernel(const int* __restrict__ top_i,
                            int* __restrict__ slot,   // [SP_] e*CAP_+pos, or -1
                            int* __restrict__ list,   // [E_*CAP_] pair index
                            int* __restrict__ count)  // [E_]
{
    __shared__ int lc[SCAN_T][E_];
    int tid = threadIdx.x;
    int cnt[E_];
    #pragma unroll
    for (int e = 0; e < E_; e++) cnt[e] = 0;
    int base = tid * CHUNK;
    for (int i = 0; i < CHUNK; i++) cnt[top_i[base + i]]++;
    #pragma unroll
    for (int e = 0; e < E_; e++) lc[tid][e] = cnt[e];
    __syncthreads();
    if (tid < E_) {
        int run = 0;
        for (int i = 0; i < SCAN_T; i++) { int c = lc[i][tid]; lc[i][tid] = run; run += c; }
        count[tid] = run;
    }
    __syncthreads();
    int off[E_];
    #pragma unroll
    for (int e = 0; e < E_; e++) off[e] = lc[tid][e];
    for (int i = 0; i < CHUNK; i++) {
        int s = base + i;
        int e = top_i[s];
        int p = off[e]++;
        if (p < CAP_) { slot[s] = e * CAP_ + p; list[e * CAP_ + p] = s; }
        else slot[s] = -1;
    }
}

// ---------------- dispatch: pack x rows into xe (bf16), zero pads ----------------
__global__ void dispatch_kernel(const float* __restrict__ x, const int* __restrict__ list,
                                const int* __restrict__ count, unsigned short* __restrict__ xe) {
    int c = blockIdx.x, e = blockIdx.y, tid = threadIdx.x;
    unsigned short* dst = xe + ((size_t)e * CAP_ + c) * D_;
    ushort4 o;
    if (c < count[e]) {
        int t = list[e * CAP_ + c] >> 1;
        float4 v = ((const float4*)(x + (size_t)t * D_))[tid];
        o.x = f2b(v.x); o.y = f2b(v.y); o.z = f2b(v.z); o.w = f2b(v.w);
    } else { o.x = 0; o.y = 0; o.z = 0; o.w = 0; }
    ((ushort4*)dst)[tid] = o;
}

// -------- transpose + fp32->bf16: src[e][r][c] -> dst[e][c][r], 64x64 tiles --------
// threads (32,8); float2 reads, ushort2 writes.
__global__ void transpose_conv64(const float* __restrict__ src, unsigned short* __restrict__ dst,
                                 int R, int C, size_t srcE, size_t dstE) {
    __shared__ float tile[64][65];
    int e = blockIdx.z;
    const float* s = src + (size_t)e * srcE;
    unsigned short* d = dst + (size_t)e * dstE;
    int tx = threadIdx.x, ty = threadIdx.y;
    int c0 = blockIdx.x * 64, r0 = blockIdx.y * 64;
    #pragma unroll
    for (int i = 0; i < 8; i++) {
        int row = ty + i * 8;
        float2 v = *(const float2*)(s + (size_t)(r0 + row) * C + c0 + 2 * tx);
        tile[row][2 * tx] = v.x; tile[row][2 * tx + 1] = v.y;
    }
    __syncthreads();
    #pragma unroll
    for (int i = 0; i < 8; i++) {
        int c = ty + i * 8;
        ushort2 o;
        o.x = f2b(tile[2 * tx][c]);
        o.y = f2b(tile[2 * tx + 1][c]);
        *(ushort2*)(d + (size_t)(c0 + c) * R + r0 + 2 * tx) = o;
    }
}

// ============================================================================
// gemm1_8p: H[e] = silu(xe@W1) * (xe@W3), 8-phase counted-vmcnt schedule.
// BM=256, BN=128, BK=64, 8 waves (2M x 4N).  T1 XCD swizzle on block ids.
// ============================================================================
#define G1_PHASE(ABUF, MP, LOADB, BBUF, STAGE, VMC)                            \
  {                                                                            \
    const unsigned short* Ah = As + (ABUF) * 16384 + wr * 8192;                \
    bf16x8 af[2][2];                                                           \
    _Pragma("unroll")                                                          \
    for (int mi = 0; mi < 2; mi++) {                                           \
      int r = ((MP) * 2 + mi) * 16 + lrow;                                     \
      _Pragma("unroll")                                                        \
      for (int kk = 0; kk < 2; kk++)                                           \
        af[mi][kk] = *(const bf16x8*)(Ah + (r * 8 + ((kk * 4 + lhi) ^ (r & 7))) * 8); \
    }                                                                          \
    if (LOADB) {                                                               \
      _Pragma("unroll")                                                        \
      for (int n = 0; n < 2; n++) {                                            \
        int rb = wc * 32 + n * 16 + lrow;                                      \
        _Pragma("unroll")                                                      \
        for (int kk = 0; kk < 2; kk++) {                                       \
          int ofs = (rb * 8 + ((kk * 4 + lhi) ^ (rb & 7))) * 8;                \
          b1f[n][kk] = *(const bf16x8*)(B1s + (BBUF) * 8192 + ofs);            \
          b3f[n][kk] = *(const bf16x8*)(B3s + (BBUF) * 8192 + ofs);            \
        }                                                                      \
      }                                                                        \
    }                                                                          \
    STAGE;                                                                     \
    __builtin_amdgcn_s_barrier();                                              \
    asm volatile("s_waitcnt lgkmcnt(0)" ::: "memory");                         \
    __builtin_amdgcn_sched_barrier(0);                                         \
    __builtin_amdgcn_s_setprio(1);                                             \
    _Pragma("unroll")                                                          \
    for (int mi = 0; mi < 2; mi++)                                             \
      _Pragma("unroll")                                                        \
      for (int n = 0; n < 2; n++)                                              \
        _Pragma("unroll")                                                      \
        for (int kk = 0; kk < 2; kk++) {                                       \
          acc1[(MP) * 2 + mi][n] = __builtin_amdgcn_mfma_f32_16x16x32_bf16(    \
              af[mi][kk], b1f[n][kk], acc1[(MP) * 2 + mi][n], 0, 0, 0);        \
          acc3[(MP) * 2 + mi][n] = __builtin_amdgcn_mfma_f32_16x16x32_bf16(    \
              af[mi][kk], b3f[n][kk], acc3[(MP) * 2 + mi][n], 0, 0, 0);        \
        }                                                                      \
    __builtin_amdgcn_s_setprio(0);                                             \
    if (VMC) asm volatile("s_waitcnt vmcnt(4)" ::: "memory");                  \
    __builtin_amdgcn_s_barrier();                                              \
  }

__global__ __launch_bounds__(512, 2) void gemm1_8p(
    const unsigned short* __restrict__ xe,    // [EG][CAP][D]
    const unsigned short* __restrict__ WT13,  // [EG][2F][D]
    unsigned short* __restrict__ H) {         // [EG][CAP][F]
    __shared__ unsigned short As[2 * 2 * 8192];   // 64KB
    __shared__ unsigned short B1s[2 * 8192];      // 32KB
    __shared__ unsigned short B3s[2 * 8192];      // 32KB
    const int tid = threadIdx.x;
    const int lane = tid & 63, wid = tid >> 6;
    const int wr = wid >> 2, wc = wid & 3;
    const int lrow = lane & 15, lhi = lane >> 4;
    // T1 bijective XCD swizzle: grid (10,32,EG) = 1280 blocks, 1280%8==0.
    const int fid = blockIdx.x + 10 * (blockIdx.y + 32 * blockIdx.z);
    const int swz = (fid & 7) * 160 + (fid >> 3);
    const int bm = swz % 10;
    const int bn = (swz / 10) % 32;
    const int e  = swz / 320;
    const int m0 = bm * 256, n0 = bn * 128;
    const unsigned short* A  = xe + (size_t)e * CAP_ * D_ + (size_t)m0 * D_;
    const unsigned short* B1 = WT13 + (size_t)e * 2 * F_ * D_ + (size_t)n0 * D_;
    const unsigned short* B3 = B1 + (size_t)F_ * D_;
    unsigned short* Hout = H + (size_t)e * CAP_ * F_;

    f32x4 acc1[8][2], acc3[8][2];
    #pragma unroll
    for (int m = 0; m < 8; m++)
        #pragma unroll
        for (int n = 0; n < 2; n++) {
            f32x4 z = {0.f, 0.f, 0.f, 0.f};
            acc1[m][n] = z; acc3[m][n] = z;
        }
    bf16x8 b1f[2][2], b3f[2][2];

    // prologue: buf0 <- K-tile 0 (A0,A1,B1,B3); buf1.B <- K-tile 1
    stage128x64(As,            A, D_, tid);
    stage128x64(As + 8192,     A + (size_t)128 * D_, D_, tid);
    stage128x64(B1s,           B1, D_, tid);
    stage128x64(B3s,           B3, D_, tid);
    stage128x64(B1s + 8192,    B1 + 64, D_, tid);
    stage128x64(B3s + 8192,    B3 + 64, D_, tid);
    asm volatile("s_waitcnt vmcnt(4)" ::: "memory");   // buf0 landed; buf1.B in flight
    __builtin_amdgcn_s_barrier();

    for (int it = 0; it < 8; ++it) {                   // NT=16, 2 K-tiles/iter
        const int t = 2 * it;
        const int k1 = (t + 1) * 64;
        const int k2 = (t + 2 < 16 ? t + 2 : 15) * 64;
        const int k3 = (t + 3 < 16 ? t + 3 : 15) * 64;
        G1_PHASE(0, 0, 1, 0, stage128x64(As + 16384,        A + k1, D_, tid), 0)
        G1_PHASE(0, 1, 0, 0, stage128x64(As + 16384 + 8192, A + (size_t)128 * D_ + k1, D_, tid), 0)
        G1_PHASE(0, 2, 0, 0, stage128x64(B1s,               B1 + k2, D_, tid), 0)
        G1_PHASE(0, 3, 0, 0, stage128x64(B3s,               B3 + k2, D_, tid), 1)
        G1_PHASE(1, 0, 1, 1, stage128x64(As,                A + k2, D_, tid), 0)
        G1_PHASE(1, 1, 0, 1, stage128x64(As + 8192,         A + (size_t)128 * D_ + k2, D_, tid), 0)
        G1_PHASE(1, 2, 0, 1, stage128x64(B1s + 8192,        B1 + k3, D_, tid), 0)
        G1_PHASE(1, 3, 0, 1, stage128x64(B3s + 8192,        B3 + k3, D_, tid), 1)
    }

    const int crow = m0 + wr * 128 + lhi * 4;
    const int ccol = n0 + wc * 32 + lrow;
    #pragma unroll
    for (int m = 0; m < 8; m++)
        #pragma unroll
        for (int n = 0; n < 2; n++)
            #pragma unroll
            for (int r = 0; r < 4; r++) {
                float g1 = acc1[m][n][r], g3 = acc3[m][n][r];
                float h = g1 / (1.f + expf(-g1)) * g3;
                Hout[(size_t)(crow + m * 16 + r) * F_ + ccol + n * 16] = f2b(h);
            }
}

// ============================================================================
// gemm2_4p: Ye[e] = H[e] @ WT2[e]^T, 4-phase counted-vmcnt schedule.
// BM=320 (CAP/320=8 -> grid 8x8x4 = 256 blocks = exact device fill),
// BN=128, BK=64, 8 waves (2M x 4N), wave-half M_rep=10 (160 rows).
// LDS 112KB: A 2buf x 40KB, B 2buf x 16KB.
//   P1 reads buf0 A(m0-4)+B; stage buf1.A<-t+1 (5 loads)
//   P2 reads buf0 A(m5-9);   stage buf0.B<-t+2 (2); vmcnt(2) [t+1 landed]
//   P3 reads buf1 A(m0-4)+B; stage buf0.A<-t+2 (5)
//   P4 reads buf1 A(m5-9);   stage buf1.B<-t+3 (2); vmcnt(2) [t+2 landed]
// ============================================================================
#define G2_PHASE(ABUF, MH, LOADB, BBUF, STAGE, VMC)                            \
  {                                                                            \
    const unsigned short* Ah = As + (ABUF) * 20480 + wr * 10240;               \
    bf16x8 af[5][2];                                                           \
    _Pragma("unroll")                                                          \
    for (int mi = 0; mi < 5; mi++) {                                           \
      int r = ((MH) * 5 + mi) * 16 + lrow;                                     \
      _Pragma("unroll")                                                        \
      for (int kk = 0; kk < 2; kk++)                                           \
        af[mi][kk] = *(const bf16x8*)(Ah + (r * 8 + ((kk * 4 + lhi) ^ (r & 7))) * 8); \
    }                                                                          \
    if (LOADB) {                                                               \
      _Pragma("unroll")                                                        \
      for (int n = 0; n < 2; n++) {                                            \
        int rb = wc * 32 + n * 16 + lrow;                                      \
        _Pragma("unroll")                                                      \
        for (int kk = 0; kk < 2; kk++)                                         \
          bf[n][kk] = *(const bf16x8*)(Bs + (BBUF) * 8192 +                    \
                                       (rb * 8 + ((kk * 4 + lhi) ^ (rb & 7))) * 8); \
      }                                                                        \
    }                                                                          \
    STAGE;                                                                     \
    __builtin_amdgcn_s_barrier();                                              \
    asm volatile("s_waitcnt lgkmcnt(0)" ::: "memory");                         \
    __builtin_amdgcn_sched_barrier(0);                                         \
    __builtin_amdgcn_s_setprio(1);                                             \
    _Pragma("unroll")                                                          \
    for (int mi = 0; mi < 5; mi++)                                             \
      _Pragma("unroll")                                                        \
      for (int n = 0; n < 2; n++)                                              \
        _Pragma("unroll")                                                      \
        for (int kk = 0; kk < 2; kk++)                                         \
          acc[(MH) * 5 + mi][n] = __builtin_amdgcn_mfma_f32_16x16x32_bf16(     \
              af[mi][kk], bf[n][kk], acc[(MH) * 5 + mi][n], 0, 0, 0);          \
    __builtin_amdgcn_s_setprio(0);                                             \
    if (VMC) asm volatile("s_waitcnt vmcnt(2)" ::: "memory");                  \
    __builtin_amdgcn_s_barrier();                                              \
  }

__global__ __launch_bounds__(512, 2) void gemm2_4p(
    const unsigned short* __restrict__ Hb,   // [EG][CAP][F]
    const unsigned short* __restrict__ WT2,  // [EG][D][F]
    unsigned short* __restrict__ Ye) {       // [EG][CAP][D]
    __shared__ unsigned short As[2 * 20480];      // 80KB  (320x64 per buf)
    __shared__ unsigned short Bs[2 * 8192];       // 32KB
    const int tid = threadIdx.x;
    const int lane = tid & 63, wid = tid >> 6;
    const int wr = wid >> 2, wc = wid & 3;
    const int lrow = lane & 15, lhi = lane >> 4;
    // T1 bijective XCD swizzle: grid (8,8,EG) = 256 blocks.
    const int fid = blockIdx.x + 8 * (blockIdx.y + 8 * blockIdx.z);
    const int swz = (fid & 7) * 32 + (fid >> 3);
    const int bm = swz & 7;
    const int bn = (swz >> 3) & 7;
    const int e  = swz >> 6;
    const int m0 = bm * 320, n0 = bn * 128;
    const unsigned short* A = Hb + (size_t)e * CAP_ * F_ + (size_t)m0 * F_;
    const unsigned short* B = WT2 + (size_t)e * D_ * F_ + (size_t)n0 * F_;
    unsigned short* C = Ye + (size_t)e * CAP_ * D_;

    f32x4 acc[10][2];
    #pragma unroll
    for (int m = 0; m < 10; m++)
        #pragma unroll
        for (int n = 0; n < 2; n++) { f32x4 z = {0.f, 0.f, 0.f, 0.f}; acc[m][n] = z; }
    bf16x8 bf[2][2];

    #define STAGE_A(BUF, KOFF)                                                  \
        { _Pragma("unroll")                                                     \
          for (int j = 0; j < 5; j++)                                           \
            stage64(As + (BUF) * 20480 + j * 4096,                              \
                    A + (size_t)(j * 64) * F_ + (KOFF), F_, tid); }
    #define STAGE_B(BUF, KOFF)                                                  \
        { stage64(Bs + (BUF) * 8192,        B + (KOFF), F_, tid);               \
          stage64(Bs + (BUF) * 8192 + 4096, B + (size_t)64 * F_ + (KOFF), F_, tid); }

    // prologue: buf0 <- K-tile 0 (A,B); buf1.B <- K-tile 1
    STAGE_A(0, 0)
    STAGE_B(0, 0)
    STAGE_B(1, 64)
    asm volatile("s_waitcnt vmcnt(2)" ::: "memory");
    __builtin_amdgcn_s_barrier();

    for (int it = 0; it < 32; ++it) {                 // NT=64, 2 K-tiles/iter
        const int t = 2 * it;
        const int k1 = (t + 1) * 64;
        const int k2 = (t + 2 < 64 ? t + 2 : 63) * 64;
        const int k3 = (t + 3 < 64 ? t + 3 : 63) * 64;
        G2_PHASE(0, 0, 1, 0, STAGE_A(1, k1), 0)
        G2_PHASE(0, 1, 0, 0, STAGE_B(0, k2), 1)
        G2_PHASE(1, 0, 1, 1, STAGE_A(0, k2), 0)
        G2_PHASE(1, 1, 0, 1, STAGE_B(1, k3), 1)
    }
    #undef STAGE_A
    #undef STAGE_B

    const int crow = m0 + wr * 160 + lhi * 4;
    const int ccol = n0 + wc * 32 + lrow;
    #pragma unroll
    for (int m = 0; m < 10; m++)
        #pragma unroll
        for (int n = 0; n < 2; n++)
            #pragma unroll
            for (int r = 0; r < 4; r++)
                C[(size_t)(crow + m * 16 + r) * D_ + ccol + n * 16] = f2b(acc[m][n][r]);
}

// ---------------- combine: out[t] = sum_k w[t,k] * Ye[slot(t,k)] ----------------
__global__ void combine_kernel(const unsigned short* __restrict__ Ye, const int* __restrict__ slot,
                               const float* __restrict__ w, float* __restrict__ out) {
    int t = blockIdx.x, tid = threadIdx.x;
    float4 r = {0.f, 0.f, 0.f, 0.f};
    #pragma unroll
    for (int k = 0; k < 2; k++) {
        int s = slot[t * 2 + k];
        if (s >= 0) {
            float wk = w[t * 2 + k];
            ushort4 y = ((const ushort4*)(Ye + (size_t)s * D_))[tid];
            r.x += wk * b2f(y.x); r.y += wk * b2f(y.y);
            r.z += wk * b2f(y.z); r.w += wk * b2f(y.w);
        }
    }
    ((float4*)(out + (size_t)t * D_))[tid] = r;
}

extern "C" void kernel_launch(void* const* d_in, const int* in_sizes, int n_in,
                              void* d_out, int out_size, void* d_ws, size_t ws_size,
                              hipStream_t stream) {
    const float* x  = (const float*)d_in[0];
    const float* Wr = (const float*)d_in[1];
    const float* W1 = (const float*)d_in[2];
    const float* W3 = (const float*)d_in[3];
    const float* W2 = (const float*)d_in[4];
    float* out = (float*)d_out;

    char* ws = (char*)d_ws;
    size_t off = 0;
    auto alloc = [&](size_t bytes) { void* p = ws + off; off += (bytes + 255) & ~(size_t)255; return p; };
    unsigned short* WT13 = (unsigned short*)alloc((size_t)E_ * 2 * F_ * D_ * 2); // [E][2F][D] bf16
    unsigned short* WT2  = (unsigned short*)alloc((size_t)E_ * D_ * F_ * 2);     // [E][D][F] bf16
    unsigned short* xe   = (unsigned short*)alloc((size_t)E_ * CAP_ * D_ * 2);
    unsigned short* Ye   = (unsigned short*)alloc((size_t)E_ * CAP_ * D_ * 2);
    unsigned short* Hg   = (unsigned short*)alloc((size_t)EG_ * CAP_ * F_ * 2);  // per-group reuse
    int*   top_i = (int*)alloc(SP_ * 4);
    float* top_w = (float*)alloc(SP_ * 4);
    int*   slot  = (int*)alloc(SP_ * 4);
    int*   list  = (int*)alloc((size_t)E_ * CAP_ * 4);
    int*   count = (int*)alloc(E_ * 4);

    dim3 tt(32, 8);
    transpose_conv64<<<dim3(F_ / 64, D_ / 64, E_), tt, 0, stream>>>(W1, WT13, D_, F_, (size_t)D_ * F_, (size_t)2 * F_ * D_);
    transpose_conv64<<<dim3(F_ / 64, D_ / 64, E_), tt, 0, stream>>>(W3, WT13 + (size_t)F_ * D_, D_, F_, (size_t)D_ * F_, (size_t)2 * F_ * D_);
    transpose_conv64<<<dim3(D_ / 64, F_ / 64, E_), tt, 0, stream>>>(W2, WT2, F_, D_, (size_t)F_ * D_, (size_t)D_ * F_);

    router_kernel<<<T_ / 4, 256, 0, stream>>>(x, Wr, top_i, top_w);
    scan_kernel<<<1, SCAN_T, 0, stream>>>(top_i, slot, list, count);
    dispatch_kernel<<<dim3(CAP_, E_), 256, 0, stream>>>(x, list, count, xe);

    for (int g = 0; g < E_ / EG_; g++) {
        size_t eo = (size_t)g * EG_;
        gemm1_8p<<<dim3(CAP_ / 256, F_ / 128, EG_), 512, 0, stream>>>(
            xe + eo * CAP_ * D_, WT13 + eo * 2 * F_ * D_, Hg);
        gemm2_4p<<<dim3(CAP_ / 320, D_ / 128, EG_), 512, 0, stream>>>(
            Hg, WT2 + eo * D_ * F_, Ye + eo * CAP_ * D_);
    }
    combine_kernel<<<T_, 256, 0, stream>>>(Ye, slot, top_w, out);
}